// Round 6
// baseline (582.566 us; speedup 1.0000x reference)
//
#include <hip/hip_runtime.h>
#include <hip/hip_bf16.h>

typedef short bf16x8 __attribute__((ext_vector_type(8)));
typedef float f32x4  __attribute__((ext_vector_type(4)));

__device__ __forceinline__ unsigned short f2bf(float f) {
  unsigned int u = __float_as_uint(f);
  u += 0x7fffu + ((u >> 16) & 1u);   // round-to-nearest-even
  return (unsigned short)(u >> 16);
}

__device__ __forceinline__ f32x4 fzero() { f32x4 z = {0.f, 0.f, 0.f, 0.f}; return z; }

#define WQKV_FRAGS (6*36*64)          /* 13824 fragment-rows */
#define WP_FRAGS   (6*12*64)          /* 4608  fragment-rows */
#define WQKV_ELEMS (WQKV_FRAGS*8)     /* 110592 bf16 elems   */

// ---------------------------------------------------------------------------
// Prepack weights fp32 -> bf16 in MFMA B-fragment order.
// B-frag for tile (kt,nt): lane l holds B[kt*32+(l>>4)*8+j][nt*16+(l&15)], j=0..7
// K-columns (192..383) get the 24^-0.5 scale baked in.
// ---------------------------------------------------------------------------
__global__ void prepack_weights(const float* __restrict__ wqkv,
                                const float* __restrict__ wproj,
                                unsigned short* __restrict__ ws) {
  int t = blockIdx.x * 256 + threadIdx.x;
  const float scale = 0.20412414523193154f;  // (192/8)^-0.5
  if (t < WQKV_FRAGS) {
    int kt  = t / (36*64);
    int rem = t - kt*(36*64);
    int nt  = rem >> 6;
    int l   = rem & 63;
    int n   = nt*16 + (l & 15);
    int k0  = kt*32 + (l >> 4)*8;
    float s = (n >= 192 && n < 384) ? scale : 1.0f;
    union { unsigned short us[8]; uint4 v; } u;
#pragma unroll
    for (int j = 0; j < 8; ++j) u.us[j] = f2bf(wqkv[(k0 + j)*576 + n] * s);
    *(uint4*)(ws + (size_t)t * 8) = u.v;
  } else if (t < WQKV_FRAGS + WP_FRAGS) {
    int t2  = t - WQKV_FRAGS;
    int kt  = t2 / (12*64);
    int rem = t2 - kt*(12*64);
    int nt  = rem >> 6;
    int l   = rem & 63;
    int n   = nt*16 + (l & 15);
    int k0  = kt*32 + (l >> 4)*8;
    union { unsigned short us[8]; uint4 v; } u;
#pragma unroll
    for (int j = 0; j < 8; ++j) u.us[j] = f2bf(wproj[(k0 + j)*192 + n]);
    *(uint4*)(ws + (size_t)WQKV_ELEMS + (size_t)t2 * 8) = u.v;
  }
}

// ---------------------------------------------------------------------------
// Fully-fused per-window kernel. 1 block = 1 window (64 tokens x 192 ch).
// 1024 threads = 16 waves (4 waves/SIMD). Same data path / layouts / numerics
// as the verified 768-thread kernel; schedule re-split so every phase divides
// exactly by 16: G1 = (ms,nt) 144 tasks -> 9/wave (af[6] only); G2' = 4 cc-
// strips x 4 d-quarters; G3 = 16 tasks -> 1/wave; G4 = 48 tasks -> 3/wave.
// ---------------------------------------------------------------------------
__launch_bounds__(1024, 4)
__global__ void win_attn_fused(const float* __restrict__ x,
                               const unsigned short* __restrict__ wqkv_sw,
                               const unsigned short* __restrict__ wp_sw,
                               const float* __restrict__ bias,
                               float* __restrict__ out) {
  __shared__ __align__(16) unsigned char smem[117760];
  unsigned short* sX   = (unsigned short*)(smem);           // 64 x 200 bf16 (X staging)
  unsigned short* sP   = (unsigned short*)(smem);           // 64 x 200 bf16 probs [cc][d] (aliases dead sX)
  unsigned short* sQ   = (unsigned short*)(smem + 25600);   // 64 x 200 bf16 [tok][d]
  unsigned short* sKt  = (unsigned short*)(smem + 51200);   // 192 x 72 bf16 [c][tok] (pre-scaled)
  unsigned short* sVt  = (unsigned short*)(smem + 78848);   // 192 x 72 bf16 [d][tok]
  unsigned short* sOut = (unsigned short*)(smem + 106496);  // 64 x 72 bf16 [tok][cc]
  float2*         sRed = (float2*)(smem + 115712);          // 4 x 64 (max,sum)

  const int tid  = threadIdx.x;
  const int lane = tid & 63;
  const int wv   = tid >> 6;      // wave 0..15
  const int l16  = lane & 15;
  const int lq   = lane >> 4;     // 0..3

  // ---- Phase 0: stage X (window is 12288 contiguous floats) -> bf16 LDS ----
  {
    const float4* xg = (const float4*)(x + (size_t)blockIdx.x * 12288);
#pragma unroll
    for (int i = 0; i < 3; ++i) {
      int idx = tid + i * 1024;         // 0..3071
      float4 v = xg[idx];
      int e = idx << 2;
      unsigned short* p = sX + (e / 192) * 200 + (e % 192);
      p[0] = f2bf(v.x); p[1] = f2bf(v.y); p[2] = f2bf(v.z); p[3] = f2bf(v.w);
    }
  }
  __syncthreads();

  // ---- G1: QKV = X @ Wqkv  (M=64, N=576, K=192) ----
  // task = (ms, nt); wave w owns ms = w&3, nt = (w>>2) + 4k, k=0..8.
  {
    const int ms1 = wv & 3;             // m-strip (16 token rows)
    const int ng1 = wv >> 2;            // nt base 0..3
    bf16x8 af[6];                       // A-frags for this wave's m-strip
#pragma unroll
    for (int kt = 0; kt < 6; ++kt)
      af[kt] = *(const bf16x8*)(sX + (ms1*16 + l16)*200 + kt*32 + lq*8);

#pragma unroll
    for (int k = 0; k < 9; ++k) {
      int nt = ng1 + 4*k;               // 0..35
      f32x4 acc = fzero();
      const bf16x8* bp = (const bf16x8*)wqkv_sw + nt*64 + lane;
#pragma unroll
      for (int kt = 0; kt < 6; ++kt)
        acc = __builtin_amdgcn_mfma_f32_16x16x32_bf16(af[kt], bp[kt * (36*64)], acc, 0, 0, 0);
      int c  = nt*16 + l16;             // qkv column (wave-uniform category per nt)
      int rb = ms1*16 + lq*4;           // token row base
      if (c < 192) {                    // Q: row-major [tok][d]
#pragma unroll
        for (int r = 0; r < 4; ++r) sQ[(rb + r)*200 + c] = f2bf(acc[r]);
      } else if (c < 384) {             // K^T: [c][tok]
#pragma unroll
        for (int r = 0; r < 4; ++r) sKt[(c - 192)*72 + rb + r] = f2bf(acc[r]);
      } else {                          // V^T: [d][tok]
#pragma unroll
        for (int r = 0; r < 4; ++r) sVt[(c - 384)*72 + rb + r] = f2bf(acc[r]);
      }
    }
  }
  __syncthreads();

  const int ccs = wv & 3;               // cc strip (16 rows) within 64-row chunk
  const int thr = wv >> 2;              // d-quarter 0..3 (48 d values each)

  // cb-invariant A-frags: V^T rows for this wave's d-quarter (3 mi-tiles)
  bf16x8 av[3][2];
#pragma unroll
  for (int mi = 0; mi < 3; ++mi)
#pragma unroll
    for (int kt = 0; kt < 2; ++kt) {
      int rd = thr*48 + mi*16 + l16;
      av[mi][kt] = *(const bf16x8*)(sVt + rd*72 + kt*32 + lq*8);
    }

  // cb-invariant Q A-frags for G3: wave task (ms3 = wv&3, ct3 = wv>>2)
  bf16x8 aq[6];
#pragma unroll
  for (int kt = 0; kt < 6; ++kt)
    aq[kt] = *(const bf16x8*)(sQ + ((wv & 3)*16 + l16)*200 + kt*32 + lq*8);

  f32x4 accF[3];                        // G4 accumulators: (ms=wv&3, nt=(wv>>2)+4k)
#pragma unroll
  for (int m = 0; m < 3; ++m) accF[m] = fzero();

  for (int cb = 0; cb < 3; ++cb) {      // attn-row chunks of 64
    // ---- G2': logits^T[d][cc] = sum_tok V^T[d][tok] * K^T[cc][tok] ----
    // lane holds 12 logits of ONE attn row cc = cb*64+ccs*16+l16,
    // at d = thr*48 + mi*16 + lq*4 + r.
    f32x4 lac[3] = {fzero(), fzero(), fzero()};
    {
      int rc = cb*64 + ccs*16 + l16;    // K^T row = this lane's attn row
#pragma unroll
      for (int kt = 0; kt < 2; ++kt) {
        bf16x8 b = *(const bf16x8*)(sKt + rc*72 + kt*32 + lq*8);
#pragma unroll
        for (int mi = 0; mi < 3; ++mi)
          lac[mi] = __builtin_amdgcn_mfma_f32_16x16x32_bf16(av[mi][kt], b, lac[mi], 0, 0, 0);
      }
    }

    // ---- softmax: in-register + shfl (combine lq) + 4-way cross exchange ----
    int ccl = ccs*16 + l16;             // chunk-local attn row 0..63
    {
      float l[12];
#pragma unroll
      for (int mi = 0; mi < 3; ++mi)
#pragma unroll
        for (int r = 0; r < 4; ++r) l[mi*4+r] = lac[mi][r];
      float mx = l[0];
#pragma unroll
      for (int i = 1; i < 12; ++i) mx = fmaxf(mx, l[i]);
      mx = fmaxf(mx, __shfl_xor(mx, 16));
      mx = fmaxf(mx, __shfl_xor(mx, 32));
      float s = 0.f;
#pragma unroll
      for (int i = 0; i < 12; ++i) { float e = __expf(l[i] - mx); l[i] = e; s += e; }
      s += __shfl_xor(s, 16);
      s += __shfl_xor(s, 32);
      if (lane < 16) sRed[thr*64 + ccl] = make_float2(mx, s);
      __syncthreads();                  // bar1
      float2 r0 = sRed[ccl], r1 = sRed[64 + ccl], r2 = sRed[128 + ccl], r3 = sRed[192 + ccl];
      float M = fmaxf(fmaxf(r0.x, r1.x), fmaxf(r2.x, r3.x));
      float S = r0.y*__expf(r0.x - M) + r1.y*__expf(r1.x - M)
              + r2.y*__expf(r2.x - M) + r3.y*__expf(r3.x - M);
      float sc = __expf(mx - M) / S;
      // write P (bf16) once: row ccl, cols d0..d0+3 per mi
#pragma unroll
      for (int mi = 0; mi < 3; ++mi) {
        int d0 = thr*48 + mi*16 + lq*4;
        union { unsigned short us[4]; uint2 v; } u;
        u.us[0] = f2bf(l[mi*4+0]*sc); u.us[1] = f2bf(l[mi*4+1]*sc);
        u.us[2] = f2bf(l[mi*4+2]*sc); u.us[3] = f2bf(l[mi*4+3]*sc);
        *(uint2*)(sP + ccl*200 + d0) = u.v;
      }
    }
    __syncthreads();                    // bar2

    // ---- G3: out_blk[tok][cc] = Q @ P^T  (M=64,N=64,K=192), 1 task/wave ----
    {
      int ct3 = wv >> 2;
      f32x4 acc = fzero();
#pragma unroll
      for (int kt = 0; kt < 6; ++kt) {
        bf16x8 b = *(const bf16x8*)(sP + (ct3*16 + l16)*200 + kt*32 + lq*8);
        acc = __builtin_amdgcn_mfma_f32_16x16x32_bf16(aq[kt], b, acc, 0, 0, 0);
      }
#pragma unroll
      for (int r = 0; r < 4; ++r)
        sOut[((wv & 3)*16 + lq*4 + r)*72 + ct3*16 + l16] = f2bf(acc[r]);
    }
    __syncthreads();                    // bar3

    // ---- G4: accF += out_blk @ Wp[cb*64 : +64, :]  (3 tasks/wave) ----
    {
      bf16x8 ao[2];
#pragma unroll
      for (int kt = 0; kt < 2; ++kt)
        ao[kt] = *(const bf16x8*)(sOut + ((wv & 3)*16 + l16)*72 + kt*32 + lq*8);
#pragma unroll
      for (int k = 0; k < 3; ++k) {
        int nt = (wv >> 2) + 4*k;       // 0..11
#pragma unroll
        for (int kt = 0; kt < 2; ++kt) {
          bf16x8 b = *((const bf16x8*)wp_sw + (((cb*2 + kt)*12) + nt)*64 + lane);
          accF[k] = __builtin_amdgcn_mfma_f32_16x16x32_bf16(ao[kt], b, accF[k], 0, 0, 0);
        }
      }
    }
    // no barrier: G2'(cb+1) is register-only; first LDS write after G4 is the
    // sRed write (disjoint from sOut), whose readers are behind bar1+bar2.
  }

  // ---- epilogue: += bias, fp32 store (3 col-tiles/wave) ----
  {
    float* op = out + (size_t)blockIdx.x * 12288;
#pragma unroll
    for (int k = 0; k < 3; ++k) {
      int nt = (wv >> 2) + 4*k;
      int e  = nt*16 + l16;
      float bv = bias[e];
#pragma unroll
      for (int r = 0; r < 4; ++r)
        op[((wv & 3)*16 + lq*4 + r)*192 + e] = accF[k][r] + bv;
    }
  }
}

extern "C" void kernel_launch(void* const* d_in, const int* in_sizes, int n_in,
                              void* d_out, int out_size, void* d_ws, size_t ws_size,
                              hipStream_t stream) {
  const float* x     = (const float*)d_in[0];
  const float* wqkv  = (const float*)d_in[1];
  const float* wproj = (const float*)d_in[2];
  const float* bproj = (const float*)d_in[3];
  unsigned short* ws = (unsigned short*)d_ws;

  int nwin = in_sizes[0] / 12288;      // B * L / 64 windows (4608)

  prepack_weights<<<72, 256, 0, stream>>>(wqkv, wproj, ws);
  win_attn_fused<<<nwin, 1024, 0, stream>>>(x, ws, ws + WQKV_ELEMS, bproj, (float*)d_out);
}